// Round 7
// baseline (239.462 us; speedup 1.0000x reference)
//
#include <hip/hip_runtime.h>
#include <hip/hip_cooperative_groups.h>

namespace cg = cooperative_groups;

#define B_ 8
#define P_ 65536
#define G_ 32
#define C_ 2
#define K_ 5
#define T1_ 0.35f
#define T2_ 0.5f
#define ALPHA_ 0.25f
#define BETA_ 0.11f
#define V0_ 0.1f
#define V1_ 0.2f

// fused path
#define NBLKF_ 512           // 2 blocks/CU target — conservative for cooperative launch
#define BPIF_ 64             // blocks per image (phases A/B)
#define APBF_ 1024           // anchors per block (4 per thread)
#define JF_ 4                // anchors per thread
// fallback path
#define NBLK_ 256            // kB blocks per image
#define CH_ 8                // top-5 chunks per (b,g)
#define CHP_ (P_ / CH_)      // 8192 anchors per chunk

// ws layout (shared by both paths):
//   [0)     Hdr (2 KB; fused: zeroed in-kernel by block 0; fallback: memsetAsync)
//   [8192)  float best_score[B_*P_]   (2 MB)
//   +2MB    int   best_idx[B_*P_]     (2 MB)
//   +2MB    double fl_n_p[2048]; double sl_n_p[2048]   (fused uses first 512 of each)
//   then    float cv5[B_*G_*CH_*5]; int ci5[B_*G_*CH_*5]
struct Hdr { int match_cnt[B_ * G_]; int c_match[B_ * G_]; };

// ---------------- numerics helpers (contract off => deterministic across call sites) ----
struct DecBox { float x1, y1, x2, y2, area; };

__device__ __forceinline__ DecBox decode_box(float4 pr, float4 lc) {
#pragma clang fp contract(off)
    DecBox d;
    float dcx = pr.x + lc.x * V0_ * pr.z;
    float dcy = pr.y + lc.y * V0_ * pr.w;
    float dw = pr.z * expf(lc.z * V1_);
    float dh = pr.w * expf(lc.w * V1_);
    d.x1 = dcx - dw * 0.5f; d.y1 = dcy - dh * 0.5f;
    d.x2 = dcx + dw * 0.5f; d.y2 = dcy + dh * 0.5f;
    d.area = (d.x2 - d.x1) * (d.y2 - d.y1);
    return d;
}

__device__ __forceinline__ float iou_dec(DecBox d, float aa,
                                         float tx1, float ty1, float tx2, float ty2) {
#pragma clang fp contract(off)
    float lx = fmaxf(tx1, d.x1), ly = fmaxf(ty1, d.y1);
    float rx = fminf(tx2, d.x2), ry = fminf(ty2, d.y2);
    float w = fmaxf(rx - lx, 0.f), hh = fmaxf(ry - ly, 0.f);
    float inter = w * hh;
    return inter / (aa + d.area - inter);
}

__device__ __forceinline__ float focal_f(float t, float x, float fiou) {
    float ce = fmaxf(x, 0.f) - x * t + log1pf(expf(-fabsf(x)));
    float a = (t * ALPHA_ + (1.f - t) * (1.f - ALPHA_)) * fiou;
    float pt = (t == 1.0f) ? x : 1.f - x;
    float om = 1.f - pt;
    return a * om * om * ce;  // GAMMA = 2
}

__device__ __forceinline__ float sml1(float p, float t) {
    float x = fabsf(p - t);
    return (x >= BETA_) ? (x - 0.5f * BETA_) : (0.5f * x * x / BETA_);
}

// top-5 by (value desc, index asc) — the stable-argsort order
__device__ __forceinline__ void top5_insert(float v, int i, float lv[5], int li[5]) {
    if ((v > lv[4]) || (v == lv[4] && i < li[4])) {
        lv[4] = v; li[4] = i;
#pragma unroll
        for (int k = 4; k > 0; --k) {
            bool sw = (lv[k] > lv[k - 1]) || (lv[k] == lv[k - 1] && li[k] < li[k - 1]);
            if (sw) {
                float tv = lv[k]; lv[k] = lv[k - 1]; lv[k - 1] = tv;
                int ti = li[k]; li[k] = li[k - 1]; li[k - 1] = ti;
            }
        }
    }
}

// ================= FUSED COOPERATIVE KERNEL (512 blocks) =================
__global__ __launch_bounds__(256, 2) void kFused(
    const float* __restrict__ loc, const float* __restrict__ conf,
    const float* __restrict__ priors, const float* __restrict__ targets,
    Hdr* __restrict__ h, float* __restrict__ best_score, int* __restrict__ best_idx,
    double* __restrict__ fl_n_p, double* __restrict__ sl_n_p,
    float* __restrict__ cv5, int* __restrict__ ci5, float* __restrict__ out) {
    cg::grid_group grid = cg::this_grid();
    int tid = threadIdx.x, bid = blockIdx.x;
    int b = bid >> 6;                        // image for phases A/B
    int a0 = (bid & (BPIF_ - 1)) * APBF_;

    __shared__ float tr[G_ * 5];
    __shared__ float gArea[G_];
    __shared__ int outf[G_];
    __shared__ int hist[G_];
    __shared__ union {
        struct { float sv[256 * 5]; int si[256 * 5]; } Dp;
        struct {
            int selp[256][5]; int nS[256];
            double aFlc[B_], aSlc[B_], aFln[B_], aSln[B_];
            int aNp[B_], aCs[B_], aNpc[B_];
        } Tp;
        double wred[8];
    } u;

    // ---- setup ----
    if (tid < G_ * 5) tr[tid] = targets[b * G_ * 5 + tid];
    if (tid < G_) hist[tid] = 0;
    if (bid == 0) { ((int*)h)[tid] = 0; ((int*)h)[256 + tid] = 0; }
    __syncthreads();
    if (tid < G_)
        gArea[tid] = (tr[tid * 5 + 2] - tr[tid * 5 + 0]) * (tr[tid * 5 + 3] - tr[tid * 5 + 1]);
    __syncthreads();

    // ---- Phase A: prior<->gt IoU best match; per-anchor state stays in registers ----
    float4 pr[JF_], lc[JF_];
    DecBox d[JF_];
    float bs[JF_];
    int bi[JF_];
#pragma unroll
    for (int j = 0; j < JF_; ++j) {
        int p = a0 + j * 256 + tid;
        pr[j] = ((const float4*)priors)[p];
        lc[j] = ((const float4*)loc)[(size_t)b * P_ + p];
        d[j] = decode_box(pr[j], lc[j]);
        float px1 = pr[j].x - pr[j].z * 0.5f, py1 = pr[j].y - pr[j].w * 0.5f;
        float px2 = pr[j].x + pr[j].z * 0.5f, py2 = pr[j].y + pr[j].w * 0.5f;
        float parea = (px2 - px1) * (py2 - py1);
        float best = -INFINITY;
        int bix = 0;
        for (int g = 0; g < G_; ++g) {
            float lx = fmaxf(tr[g * 5 + 0], px1), ly = fmaxf(tr[g * 5 + 1], py1);
            float rx = fminf(tr[g * 5 + 2], px2), ry = fminf(tr[g * 5 + 3], py2);
            float w = fmaxf(rx - lx, 0.f), hh = fmaxf(ry - ly, 0.f);
            float inter = w * hh;
            float v = inter / (gArea[g] + parea - inter);
            if (v > best) { best = v; bix = g; }  // first-max == jnp.argmax
        }
        bs[j] = best; bi[j] = bix;
        best_score[b * P_ + p] = best;
        best_idx[b * P_ + p] = bix;
        if (best > T1_) atomicAdd(&hist[bix], 1);
    }
    __syncthreads();
    grid.sync();  // #1: header zeroed everywhere, block hists complete
    if (tid < G_ && hist[tid]) atomicAdd(&h->match_cnt[b * G_ + tid], hist[tid]);
    grid.sync();  // #2: match_cnt final

    // ---- Phase B: normal losses + c_match (anchor state from registers) ----
    if (tid < G_) {
        outf[tid] = (h->match_cnt[b * G_ + tid] < K_) ? 1 : 0;
        hist[tid] = 0;
    }
    __syncthreads();
    double fl = 0.0, sl = 0.0;
#pragma unroll
    for (int j = 0; j < JF_; ++j) {
        int p = a0 + j * 256 + tid;
        bool n_pos = bs[j] > T1_;
        float cmax = -INFINITY, mbest = -INFINITY;
        int mg = 0;
        for (int g = 0; g < G_; ++g) {
            float v = iou_dec(d[j], gArea[g], tr[g * 5 + 0], tr[g * 5 + 1],
                              tr[g * 5 + 2], tr[g * 5 + 3]);
            cmax = fmaxf(cmax, v);
            bool kill = outf[g] && (bi[j] == g) && n_pos;
            float v2 = kill ? 0.f : v;
            float m = outf[g] ? v2 : -1.f;
            if (m > mbest) { mbest = m; mg = g; }  // first-max
        }
        if (mbest > T2_) atomicAdd(&hist[mg], 1);
        bool ignore = (cmax > T2_) && (bs[j] < T1_);
        bool neg = !(n_pos || ignore);
        int lab = (int)tr[bi[j] * 5 + 4];
        float2 cf = ((const float2*)conf)[(size_t)b * P_ + p];
        float cfs[2] = {cf.x, cf.y};
#pragma unroll
        for (int c = 0; c < C_; ++c) {
            if (n_pos) fl += (double)focal_f((c == lab) ? 1.f : 0.f, cfs[c], 1.f);
            else if (neg) fl += (double)focal_f(0.f, cfs[c], 1.f);
        }
        if (n_pos) {
            float tx1 = tr[bi[j] * 5], ty1 = tr[bi[j] * 5 + 1];
            float tx2 = tr[bi[j] * 5 + 2], ty2 = tr[bi[j] * 5 + 3];
            float e0 = ((tx1 + tx2) * 0.5f - pr[j].x) / (V0_ * pr[j].z);
            float e1 = ((ty1 + ty2) * 0.5f - pr[j].y) / (V0_ * pr[j].w);
            float e2 = logf((tx2 - tx1) / pr[j].z) / V1_;
            float e3 = logf((ty2 - ty1) / pr[j].w) / V1_;
            sl += (double)sml1(lc[j].x, e0) + (double)sml1(lc[j].y, e1) +
                  (double)sml1(lc[j].z, e2) + (double)sml1(lc[j].w, e3);
        }
    }
    {
        int lane = tid & 63, w = tid >> 6;
        for (int off = 32; off > 0; off >>= 1) {
            fl += __shfl_down(fl, off, 64);
            sl += __shfl_down(sl, off, 64);
        }
        if (lane == 0) { u.wred[w] = fl; u.wred[4 + w] = sl; }
        __syncthreads();
        if (tid == 0) fl_n_p[bid] = u.wred[0] + u.wred[1] + u.wred[2] + u.wred[3];
        if (tid == 1) sl_n_p[bid] = u.wred[4] + u.wred[5] + u.wred[6] + u.wred[7];
        if (tid < G_ && hist[tid]) atomicAdd(&h->c_match[b * G_ + tid], hist[tid]);
    }
    grid.sync();  // #3: c_match + partials final

    // ---- Phase D: 4 (b,g,ch) top-5 tasks per block, early-exit on n<=0 ----
    for (int r = 0; r < 4; ++r) {
        int task = bid * 4 + r;
        int tb = task >> 8, tg = (task >> 3) & 31, tch = task & (CH_ - 1);
        int mc = h->match_cnt[tb * G_ + tg];
        int cm = h->c_match[tb * G_ + tg];
        int n = (mc < K_) ? min(cm, K_ - mc) : 0;
        if (n > 0) {  // uniform per block
            const float* tgp = targets + (tb * G_ + tg) * 5;
            float tx1 = tgp[0], ty1 = tgp[1], tx2 = tgp[2], ty2 = tgp[3];
            float aa = (tx2 - tx1) * (ty2 - ty1);
            float lv[5];
            int li[5];
#pragma unroll
            for (int k = 0; k < 5; ++k) { lv[k] = -INFINITY; li[k] = 0x7fffffff; }
            int base = tch * CHP_;
            for (int it = 0; it < CHP_ / 256; ++it) {
                int p = base + it * 256 + tid;
                int pbi = best_idx[tb * P_ + p];
                float pbs = best_score[tb * P_ + p];
                float v2;
                if (pbi == tg && pbs > T1_) v2 = 0.f;  // kill (outface true here)
                else {
                    float4 prr = ((const float4*)priors)[p];
                    float4 lcc = ((const float4*)loc)[(size_t)tb * P_ + p];
                    v2 = iou_dec(decode_box(prr, lcc), aa, tx1, ty1, tx2, ty2);
                }
                top5_insert(v2, p, lv, li);
            }
#pragma unroll
            for (int k = 0; k < 5; ++k) { u.Dp.sv[tid * 5 + k] = lv[k]; u.Dp.si[tid * 5 + k] = li[k]; }
            __syncthreads();
            for (int str = 128; str > 0; str >>= 1) {
                if (tid < str) {
                    int a = 0, c = 0;
                    float ov[5];
                    int oi[5];
#pragma unroll
                    for (int k = 0; k < 5; ++k) {
                        float va = u.Dp.sv[tid * 5 + a], vb = u.Dp.sv[(tid + str) * 5 + c];
                        int ia = u.Dp.si[tid * 5 + a], ib = u.Dp.si[(tid + str) * 5 + c];
                        bool ta = (va > vb) || (va == vb && ia < ib);
                        ov[k] = ta ? va : vb;
                        oi[k] = ta ? ia : ib;
                        if (ta) a++; else c++;
                    }
#pragma unroll
                    for (int k = 0; k < 5; ++k) { u.Dp.sv[tid * 5 + k] = ov[k]; u.Dp.si[tid * 5 + k] = oi[k]; }
                }
                __syncthreads();
            }
            if (tid == 0) {
#pragma unroll
                for (int k = 0; k < 5; ++k) {
                    cv5[((tb * G_ + tg) * CH_ + tch) * 5 + k] = u.Dp.sv[k];
                    ci5[((tb * G_ + tg) * CH_ + tch) * 5 + k] = u.Dp.si[k];
                }
            }
        }
        __syncthreads();
    }
    grid.sync();  // #4: cv5/ci5 final

    // ---- Phase Tail: block 0 merges, resolves overrides, finalizes ----
    if (bid != 0) return;
    {
        int t = tid, tb = t >> 5, tg = t & 31;
        int mc = h->match_cnt[t];
        int cm = h->c_match[t];
        int n = (mc < K_) ? min(cm, K_ - mc) : 0;
        u.Tp.nS[t] = n;
        float mv[5];
        int mi[5];
#pragma unroll
        for (int k = 0; k < 5; ++k) { mv[k] = -INFINITY; mi[k] = 0x7fffffff; }
        if (n > 0) {
            for (int ch = 0; ch < CH_; ++ch)
#pragma unroll
                for (int k = 0; k < 5; ++k)
                    top5_insert(cv5[(t * CH_ + ch) * 5 + k], ci5[(t * CH_ + ch) * 5 + k], mv, mi);
        }
#pragma unroll
        for (int k = 0; k < 5; ++k) u.Tp.selp[t][k] = (k < n) ? mi[k] : -1;
        __syncthreads();

        double flc = 0.0, slc = 0.0;
        int alive = 0;
        float tg0 = targets[t * 5 + 0], tg1 = targets[t * 5 + 1];
        float tg2 = targets[t * 5 + 2], tg3 = targets[t * 5 + 3];
        float labf = targets[t * 5 + 4];
        int labi = (int)labf;
        for (int k = 0; k < n; ++k) {
            int p = mi[k];
            bool dead = false;
            for (int g2 = tg + 1; g2 < G_; ++g2) {
                int q = tb * G_ + g2;
                int n2 = u.Tp.nS[q];
                for (int k2 = 0; k2 < n2; ++k2)
                    if (u.Tp.selp[q][k2] == p) dead = true;
            }
            if (!dead) {
                alive++;
                float4 prr = ((const float4*)priors)[p];
                float4 lcc = ((const float4*)loc)[(size_t)tb * P_ + p];
                float e0 = ((tg0 + tg2) * 0.5f - prr.x) / (V0_ * prr.z);
                float e1 = ((tg1 + tg3) * 0.5f - prr.y) / (V0_ * prr.w);
                float e2 = logf((tg2 - tg0) / prr.z) / V1_;
                float e3 = logf((tg3 - tg1) / prr.w) / V1_;
                slc += (double)sml1(lcc.x, e0) + (double)sml1(lcc.y, e1) +
                       (double)sml1(lcc.z, e2) + (double)sml1(lcc.w, e3);
                float2 cf = ((const float2*)conf)[(size_t)tb * P_ + p];
                float cfs[2] = {cf.x, cf.y};
#pragma unroll
                for (int c = 0; c < C_; ++c) {
                    float tt = (c == labi) ? labf : 0.f;  // labels[g] * one_hot
                    flc += (double)focal_f(tt, cfs[c], mv[k]);
                }
            }
        }

        // per-b reductions within 32-thread subgroups (64 partial slots per image)
        int rmc = mc, rn = n, ra = alive;
        double rf = flc, rs = slc;
        double pf = 0.0, ps = 0.0;
        for (int j = 0; j < 2; ++j) {
            pf += fl_n_p[tb * BPIF_ + tg * 2 + j];
            ps += sl_n_p[tb * BPIF_ + tg * 2 + j];
        }
        for (int off = 16; off > 0; off >>= 1) {
            rmc += __shfl_down(rmc, off, 32);
            rn += __shfl_down(rn, off, 32);
            ra += __shfl_down(ra, off, 32);
            rf += __shfl_down(rf, off, 32);
            rs += __shfl_down(rs, off, 32);
            pf += __shfl_down(pf, off, 32);
            ps += __shfl_down(ps, off, 32);
        }
        if (tg == 0) {
            u.Tp.aNp[tb] = rmc; u.Tp.aCs[tb] = rn; u.Tp.aNpc[tb] = ra;
            u.Tp.aFlc[tb] = rf; u.Tp.aSlc[tb] = rs; u.Tp.aFln[tb] = pf; u.Tp.aSln[tb] = ps;
        }
        __syncthreads();
        if (t == 0) {
            double sll = 0.0, scl = 0.0;
            for (int b2 = 0; b2 < B_; ++b2) {
                double l_loc = 0.0, l_cls = 0.0;
                int npos = u.Tp.aNp[b2];
                if (npos > 0) {
                    l_cls += u.Tp.aFln[b2] / (double)npos;
                    l_loc += u.Tp.aSln[b2] / (double)npos;
                }
                int csum = u.Tp.aCs[b2];
                if (csum > 0) {
                    int npc = (u.Tp.aNpc[b2] > 1) ? u.Tp.aNpc[b2] : 1;
                    l_loc += u.Tp.aSlc[b2] / (double)npc;
                    l_cls += u.Tp.aFlc[b2] / (double)csum;
                }
                sll += l_loc;
                scl += l_cls;
            }
            out[0] = (float)(sll / B_);
            out[1] = (float)(scl / B_);
        }
    }
}

// ================= FALLBACK PATH (proven R5 pipeline, 56.9 µs) =================
__device__ __forceinline__ float iou_corner(float ax1, float ay1, float ax2, float ay2,
                                            float bx1, float by1, float bx2, float by2) {
    float lx = fmaxf(ax1, bx1), ly = fmaxf(ay1, by1);
    float rx = fminf(ax2, bx2), ry = fminf(ay2, by2);
    float w = fmaxf(rx - lx, 0.f), hh = fmaxf(ry - ly, 0.f);
    float inter = w * hh;
    float aa = (ax2 - ax1) * (ay2 - ay1);
    float ab = (bx2 - bx1) * (by2 - by1);
    return inter / (aa + ab - inter);
}

__global__ __launch_bounds__(256) void kA(const float* __restrict__ priors,
                                          const float* __restrict__ targets, Hdr* h,
                                          float* __restrict__ best_score,
                                          int* __restrict__ best_idx) {
    int tid = threadIdx.x;
    int p = blockIdx.x * 256 + tid, b = blockIdx.y;
    __shared__ float tr[G_ * 5];
    __shared__ int hist[G_];
    if (tid < G_ * 5) tr[tid] = targets[b * G_ * 5 + tid];
    if (tid < G_) hist[tid] = 0;
    __syncthreads();
    float4 pr = ((const float4*)priors)[p];
    float px1 = pr.x - pr.z * 0.5f, py1 = pr.y - pr.w * 0.5f;
    float px2 = pr.x + pr.z * 0.5f, py2 = pr.y + pr.w * 0.5f;
    float best = -INFINITY;
    int bi = 0;
    for (int g = 0; g < G_; ++g) {
        float v = iou_corner(tr[g * 5], tr[g * 5 + 1], tr[g * 5 + 2], tr[g * 5 + 3],
                             px1, py1, px2, py2);
        if (v > best) { best = v; bi = g; }
    }
    best_score[b * P_ + p] = best;
    best_idx[b * P_ + p] = bi;
    if (best > T1_) atomicAdd(&hist[bi], 1);
    __syncthreads();
    if (tid < G_ && hist[tid]) atomicAdd(&h->match_cnt[b * G_ + tid], hist[tid]);
}

__global__ __launch_bounds__(256) void kB(
    const float* __restrict__ loc, const float* __restrict__ conf,
    const float* __restrict__ priors, const float* __restrict__ targets,
    Hdr* __restrict__ h,
    const float* __restrict__ best_score, const int* __restrict__ best_idx,
    double* __restrict__ fl_n_p, double* __restrict__ sl_n_p) {
    int tid = threadIdx.x, b = blockIdx.y;
    int p = blockIdx.x * 256 + tid;
    __shared__ float tr[G_ * 5];
    __shared__ float sArea[G_];
    __shared__ int outf[G_];
    __shared__ int hist[G_];
    __shared__ double wred[8];
    if (tid < G_ * 5) tr[tid] = targets[b * G_ * 5 + tid];
    if (tid < G_) {
        const float* tg = targets + (b * G_ + tid) * 5;
        sArea[tid] = (tg[2] - tg[0]) * (tg[3] - tg[1]);
        hist[tid] = 0;
        outf[tid] = (h->match_cnt[b * G_ + tid] < K_) ? 1 : 0;
    }
    __syncthreads();
    float4 pr = ((const float4*)priors)[p];
    float4 lc = ((const float4*)loc)[(size_t)b * P_ + p];
    float bs = best_score[b * P_ + p];
    int bi = best_idx[b * P_ + p];
    DecBox d = decode_box(pr, lc);
    bool n_pos = bs > T1_;
    float cmax = -INFINITY, mbest = -INFINITY;
    int mg = 0;
    for (int g = 0; g < G_; ++g) {
        float v = iou_dec(d, sArea[g], tr[g * 5], tr[g * 5 + 1], tr[g * 5 + 2], tr[g * 5 + 3]);
        cmax = fmaxf(cmax, v);
        bool kill = outf[g] && (bi == g) && n_pos;
        float v2 = kill ? 0.f : v;
        float m = outf[g] ? v2 : -1.f;
        if (m > mbest) { mbest = m; mg = g; }
    }
    if (mbest > T2_) atomicAdd(&hist[mg], 1);
    bool ignore = (cmax > T2_) && (bs < T1_);
    bool neg = !(n_pos || ignore);
    double fl = 0.0, sl = 0.0;
    int lab = (int)tr[bi * 5 + 4];
    float2 cf = ((const float2*)conf)[(size_t)b * P_ + p];
    float cfs[2] = {cf.x, cf.y};
#pragma unroll
    for (int c = 0; c < C_; ++c) {
        if (n_pos) fl += (double)focal_f((c == lab) ? 1.f : 0.f, cfs[c], 1.f);
        else if (neg) fl += (double)focal_f(0.f, cfs[c], 1.f);
    }
    if (n_pos) {
        float tx1 = tr[bi * 5], ty1 = tr[bi * 5 + 1];
        float tx2 = tr[bi * 5 + 2], ty2 = tr[bi * 5 + 3];
        float e0 = ((tx1 + tx2) * 0.5f - pr.x) / (V0_ * pr.z);
        float e1 = ((ty1 + ty2) * 0.5f - pr.y) / (V0_ * pr.w);
        float e2 = logf((tx2 - tx1) / pr.z) / V1_;
        float e3 = logf((ty2 - ty1) / pr.w) / V1_;
        sl = (double)sml1(lc.x, e0) + (double)sml1(lc.y, e1) +
             (double)sml1(lc.z, e2) + (double)sml1(lc.w, e3);
    }
    int lane = tid & 63, w = tid >> 6;
    for (int off = 32; off > 0; off >>= 1) {
        fl += __shfl_down(fl, off, 64);
        sl += __shfl_down(sl, off, 64);
    }
    if (lane == 0) { wred[w] = fl; wred[4 + w] = sl; }
    __syncthreads();
    if (tid == 0) fl_n_p[b * NBLK_ + blockIdx.x] = wred[0] + wred[1] + wred[2] + wred[3];
    if (tid == 1) sl_n_p[b * NBLK_ + blockIdx.x] = wred[4] + wred[5] + wred[6] + wred[7];
    if (tid < G_ && hist[tid]) atomicAdd(&h->c_match[b * G_ + tid], hist[tid]);
}

__global__ __launch_bounds__(256) void kD(
    const float* __restrict__ loc, const float* __restrict__ priors,
    const float* __restrict__ targets, const Hdr* __restrict__ h,
    const float* __restrict__ best_score, const int* __restrict__ best_idx,
    float* __restrict__ cv5, int* __restrict__ ci5) {
    int tid = threadIdx.x, b = blockIdx.y;
    int g = blockIdx.x >> 3, ch = blockIdx.x & (CH_ - 1);
    int mc = h->match_cnt[b * G_ + g];
    int cm = h->c_match[b * G_ + g];
    int n = (mc < K_) ? min(cm, K_ - mc) : 0;
    if (n <= 0) return;
    float tx1 = targets[(b * G_ + g) * 5 + 0], ty1 = targets[(b * G_ + g) * 5 + 1];
    float tx2 = targets[(b * G_ + g) * 5 + 2], ty2 = targets[(b * G_ + g) * 5 + 3];
    float aa = (tx2 - tx1) * (ty2 - ty1);
    float lv[5];
    int li[5];
#pragma unroll
    for (int k = 0; k < 5; ++k) { lv[k] = -INFINITY; li[k] = 0x7fffffff; }
    int base = ch * CHP_;
    for (int it = 0; it < CHP_ / 256; ++it) {
        int p = base + it * 256 + tid;
        int bi = best_idx[b * P_ + p];
        float bs = best_score[b * P_ + p];
        float v2;
        if (bi == g && bs > T1_) v2 = 0.f;
        else {
            float4 pr = ((const float4*)priors)[p];
            float4 lc = ((const float4*)loc)[(size_t)b * P_ + p];
            v2 = iou_dec(decode_box(pr, lc), aa, tx1, ty1, tx2, ty2);
        }
        top5_insert(v2, p, lv, li);
    }
    __shared__ float sv[256 * 5];
    __shared__ int si[256 * 5];
#pragma unroll
    for (int k = 0; k < 5; ++k) { sv[tid * 5 + k] = lv[k]; si[tid * 5 + k] = li[k]; }
    __syncthreads();
    for (int str = 128; str > 0; str >>= 1) {
        if (tid < str) {
            int a = 0, c = 0;
            float ov[5];
            int oi[5];
#pragma unroll
            for (int k = 0; k < 5; ++k) {
                float va = sv[tid * 5 + a], vb = sv[(tid + str) * 5 + c];
                int ia = si[tid * 5 + a], ib = si[(tid + str) * 5 + c];
                bool ta = (va > vb) || (va == vb && ia < ib);
                ov[k] = ta ? va : vb;
                oi[k] = ta ? ia : ib;
                if (ta) a++; else c++;
            }
#pragma unroll
            for (int k = 0; k < 5; ++k) { sv[tid * 5 + k] = ov[k]; si[tid * 5 + k] = oi[k]; }
        }
        __syncthreads();
    }
    if (tid == 0) {
#pragma unroll
        for (int k = 0; k < 5; ++k) {
            cv5[((b * G_ + g) * CH_ + ch) * 5 + k] = sv[k];
            ci5[((b * G_ + g) * CH_ + ch) * 5 + k] = si[k];
        }
    }
}

__global__ __launch_bounds__(256) void kTail(
    const float* __restrict__ loc, const float* __restrict__ conf,
    const float* __restrict__ priors, const float* __restrict__ targets,
    const Hdr* __restrict__ h,
    const double* __restrict__ fl_n_p, const double* __restrict__ sl_n_p,
    const float* __restrict__ cv5, const int* __restrict__ ci5,
    float* __restrict__ out) {
    int t = threadIdx.x, b = t >> 5, g = t & 31;
    __shared__ int selp[256][5];
    __shared__ int nS[256];
    __shared__ double aFlc[B_], aSlc[B_], aFln[B_], aSln[B_];
    __shared__ int aNp[B_], aCs[B_], aNpc[B_];

    int mc = h->match_cnt[t];
    int cm = h->c_match[t];
    int n = (mc < K_) ? min(cm, K_ - mc) : 0;
    nS[t] = n;
    float mv[5];
    int mi[5];
#pragma unroll
    for (int k = 0; k < 5; ++k) { mv[k] = -INFINITY; mi[k] = 0x7fffffff; }
    if (n > 0) {
        for (int ch = 0; ch < CH_; ++ch)
#pragma unroll
            for (int k = 0; k < 5; ++k)
                top5_insert(cv5[(t * CH_ + ch) * 5 + k], ci5[(t * CH_ + ch) * 5 + k], mv, mi);
    }
#pragma unroll
    for (int k = 0; k < 5; ++k) selp[t][k] = (k < n) ? mi[k] : -1;
    __syncthreads();

    double flc = 0.0, slc = 0.0;
    int alive = 0;
    float tg0 = targets[t * 5 + 0], tg1 = targets[t * 5 + 1];
    float tg2 = targets[t * 5 + 2], tg3 = targets[t * 5 + 3];
    float labf = targets[t * 5 + 4];
    int labi = (int)labf;
    for (int k = 0; k < n; ++k) {
        int p = mi[k];
        bool dead = false;
        for (int g2 = g + 1; g2 < G_; ++g2) {
            int q = b * G_ + g2;
            int n2 = nS[q];
            for (int k2 = 0; k2 < n2; ++k2)
                if (selp[q][k2] == p) dead = true;
        }
        if (!dead) {
            alive++;
            float4 pr = ((const float4*)priors)[p];
            float4 lc = ((const float4*)loc)[(size_t)b * P_ + p];
            float e0 = ((tg0 + tg2) * 0.5f - pr.x) / (V0_ * pr.z);
            float e1 = ((tg1 + tg3) * 0.5f - pr.y) / (V0_ * pr.w);
            float e2 = logf((tg2 - tg0) / pr.z) / V1_;
            float e3 = logf((tg3 - tg1) / pr.w) / V1_;
            slc += (double)sml1(lc.x, e0) + (double)sml1(lc.y, e1) +
                   (double)sml1(lc.z, e2) + (double)sml1(lc.w, e3);
            float2 cf = ((const float2*)conf)[(size_t)b * P_ + p];
            float cfs[2] = {cf.x, cf.y};
#pragma unroll
            for (int c = 0; c < C_; ++c) {
                float tt = (c == labi) ? labf : 0.f;
                flc += (double)focal_f(tt, cfs[c], mv[k]);
            }
        }
    }

    int rmc = mc, rn = n, ra = alive;
    double rf = flc, rs = slc;
    double pf = 0.0, ps = 0.0;
    for (int j = 0; j < 8; ++j) { pf += fl_n_p[t * 8 + j]; ps += sl_n_p[t * 8 + j]; }
    for (int off = 16; off > 0; off >>= 1) {
        rmc += __shfl_down(rmc, off, 32);
        rn += __shfl_down(rn, off, 32);
        ra += __shfl_down(ra, off, 32);
        rf += __shfl_down(rf, off, 32);
        rs += __shfl_down(rs, off, 32);
        pf += __shfl_down(pf, off, 32);
        ps += __shfl_down(ps, off, 32);
    }
    if (g == 0) {
        aNp[b] = rmc; aCs[b] = rn; aNpc[b] = ra;
        aFlc[b] = rf; aSlc[b] = rs; aFln[b] = pf; aSln[b] = ps;
    }
    __syncthreads();
    if (t == 0) {
        double sll = 0.0, scl = 0.0;
        for (int b2 = 0; b2 < B_; ++b2) {
            double l_loc = 0.0, l_cls = 0.0;
            int npos = aNp[b2];
            if (npos > 0) {
                l_cls += aFln[b2] / (double)npos;
                l_loc += aSln[b2] / (double)npos;
            }
            int csum = aCs[b2];
            if (csum > 0) {
                int npc = (aNpc[b2] > 1) ? aNpc[b2] : 1;
                l_loc += aSlc[b2] / (double)npc;
                l_cls += aFlc[b2] / (double)csum;
            }
            sll += l_loc;
            scl += l_cls;
        }
        out[0] = (float)(sll / B_);
        out[1] = (float)(scl / B_);
    }
}

extern "C" void kernel_launch(void* const* d_in, const int* in_sizes, int n_in,
                              void* d_out, int out_size, void* d_ws, size_t ws_size,
                              hipStream_t stream) {
    (void)in_sizes; (void)n_in; (void)out_size; (void)ws_size;
    const float* loc = (const float*)d_in[0];
    const float* conf = (const float*)d_in[1];
    const float* priors = (const float*)d_in[2];
    const float* targets = (const float*)d_in[3];
    float* out = (float*)d_out;
    char* ws = (char*)d_ws;
    Hdr* h = (Hdr*)ws;
    float* best_score = (float*)(ws + 8192);
    int* best_idx = (int*)(ws + 8192 + (size_t)B_ * P_ * 4);
    double* fl_n_p = (double*)(ws + 8192 + (size_t)B_ * P_ * 8);
    double* sl_n_p = fl_n_p + B_ * NBLK_;   // 2048 slots each (fused uses first 512)
    float* cv5 = (float*)(sl_n_p + B_ * NBLK_);
    int* ci5 = (int*)(cv5 + B_ * G_ * CH_ * 5);

    // --- pre-flight: can we cooperatively launch 512 blocks? (host-side, capture-safe)
    int dev = 0;
    hipGetDevice(&dev);
    int coopAttr = 0;
    hipDeviceGetAttribute(&coopAttr, hipDeviceAttributeCooperativeLaunch, dev);
    int numCU = 0;
    hipDeviceGetAttribute(&numCU, hipDeviceAttributeMultiprocessorCount, dev);
    int occ = 0;
    hipError_t qerr = hipOccupancyMaxActiveBlocksPerMultiprocessor(&occ, kFused, 256, 0);

    hipError_t lerr = hipErrorUnknown;
    if (coopAttr && qerr == hipSuccess && occ > 0 && (long)occ * numCU >= NBLKF_) {
        void* args[] = {&loc, &conf, &priors, &targets, &h, &best_score, &best_idx,
                        &fl_n_p, &sl_n_p, &cv5, &ci5, &out};
        lerr = hipLaunchCooperativeKernel((const void*)kFused, dim3(NBLKF_), dim3(256),
                                          args, 0, stream);
    }
    if (lerr != hipSuccess) {
        // fallback: proven R5 pipeline
        hipMemsetAsync(h, 0, sizeof(Hdr), stream);
        kA<<<dim3(NBLK_, B_), 256, 0, stream>>>(priors, targets, h, best_score, best_idx);
        kB<<<dim3(NBLK_, B_), 256, 0, stream>>>(loc, conf, priors, targets, h,
                                                best_score, best_idx, fl_n_p, sl_n_p);
        kD<<<dim3(G_ * CH_, B_), 256, 0, stream>>>(loc, priors, targets, h,
                                                   best_score, best_idx, cv5, ci5);
        kTail<<<1, 256, 0, stream>>>(loc, conf, priors, targets, h, fl_n_p, sl_n_p,
                                     cv5, ci5, out);
    }
}

// Round 8
// 90.459 us; speedup vs baseline: 2.6472x; 2.6472x over previous
//
#include <hip/hip_runtime.h>

#define B_ 8
#define P_ 65536
#define G_ 32
#define C_ 2
#define K_ 5
#define T1_ 0.35f
#define T2_ 0.5f
#define ALPHA_ 0.25f
#define BETA_ 0.11f
#define V0_ 0.1f
#define V1_ 0.2f

#define NBLK_ 256                 // blocks per image for kA/kB
#define NBLKB_ (B_ * NBLK_)       // 2048
#define CH_ 8                     // top-5 chunks per (b,g)
#define CHP_ (P_ / CH_)           // 8192 anchors per chunk
#define NTASK_ (B_ * G_ * CH_)    // 2048 kDT blocks

// ws layout (all plain-store scratch; nothing needs pre-zeroing except `done`,
// which kA zeroes one dispatch ahead of its use):
//   [0)      float  best_score[B_*P_]      2 MB
//   +2MB     int    best_idx[B_*P_]        2 MB
//   +4MB     double fl_n_p[2048]           16 KB
//   +..      double sl_n_p[2048]           16 KB
//   +..      float  cv5[B_*G_*CH_*5]       40 KB
//   +..      int    ci5[B_*G_*CH_*5]       40 KB
//   +..      int    histA[2048*32]         256 KB   per-kA-block match hist
//   +..      int    histC[2048*32]         256 KB   per-kB-block c_match hist
//   +..      int    match_final[256]       1 KB
//   +..      int    cm_final[256]          1 KB
//   +..      int    done[1]

// ---------------- numerics helpers (contract off => deterministic across call sites) ----
struct DecBox { float x1, y1, x2, y2, area; };

__device__ __forceinline__ DecBox decode_box(float4 pr, float4 lc) {
#pragma clang fp contract(off)
    DecBox d;
    float dcx = pr.x + lc.x * V0_ * pr.z;
    float dcy = pr.y + lc.y * V0_ * pr.w;
    float dw = pr.z * expf(lc.z * V1_);
    float dh = pr.w * expf(lc.w * V1_);
    d.x1 = dcx - dw * 0.5f; d.y1 = dcy - dh * 0.5f;
    d.x2 = dcx + dw * 0.5f; d.y2 = dcy + dh * 0.5f;
    d.area = (d.x2 - d.x1) * (d.y2 - d.y1);
    return d;
}

__device__ __forceinline__ float iou_dec(DecBox d, float aa,
                                         float tx1, float ty1, float tx2, float ty2) {
#pragma clang fp contract(off)
    float lx = fmaxf(tx1, d.x1), ly = fmaxf(ty1, d.y1);
    float rx = fminf(tx2, d.x2), ry = fminf(ty2, d.y2);
    float w = fmaxf(rx - lx, 0.f), hh = fmaxf(ry - ly, 0.f);
    float inter = w * hh;
    return inter / (aa + d.area - inter);
}

__device__ __forceinline__ float focal_f(float t, float x, float fiou) {
    float ce = fmaxf(x, 0.f) - x * t + log1pf(expf(-fabsf(x)));
    float a = (t * ALPHA_ + (1.f - t) * (1.f - ALPHA_)) * fiou;
    float pt = (t == 1.0f) ? x : 1.f - x;
    float om = 1.f - pt;
    return a * om * om * ce;  // GAMMA = 2
}

__device__ __forceinline__ float sml1(float p, float t) {
    float x = fabsf(p - t);
    return (x >= BETA_) ? (x - 0.5f * BETA_) : (0.5f * x * x / BETA_);
}

// top-5 by (value desc, index asc) — the stable-argsort order
__device__ __forceinline__ void top5_insert(float v, int i, float lv[5], int li[5]) {
    if ((v > lv[4]) || (v == lv[4] && i < li[4])) {
        lv[4] = v; li[4] = i;
#pragma unroll
        for (int k = 4; k > 0; --k) {
            bool sw = (lv[k] > lv[k - 1]) || (lv[k] == lv[k - 1] && li[k] < li[k - 1]);
            if (sw) {
                float tv = lv[k]; lv[k] = lv[k - 1]; lv[k - 1] = tv;
                int ti = li[k]; li[k] = li[k - 1]; li[k - 1] = ti;
            }
        }
    }
}

// ---------------- kA: best match per anchor; per-block hist (plain stores) -------------
__global__ __launch_bounds__(256) void kA(const float* __restrict__ priors,
                                          const float* __restrict__ targets,
                                          float* __restrict__ best_score,
                                          int* __restrict__ best_idx,
                                          int* __restrict__ histA,
                                          int* __restrict__ done) {
    int tid = threadIdx.x, blk = blockIdx.x, b = blockIdx.y;
    __shared__ float tr[G_ * 5];
    __shared__ float gA[G_];
    __shared__ int hist[G_];
    if (tid < G_ * 5) tr[tid] = targets[b * G_ * 5 + tid];
    if (tid < G_) hist[tid] = 0;
    __syncthreads();
    if (tid < G_)
        gA[tid] = (tr[tid * 5 + 2] - tr[tid * 5 + 0]) * (tr[tid * 5 + 3] - tr[tid * 5 + 1]);
    __syncthreads();
    int p = blk * 256 + tid;
    float4 pr = ((const float4*)priors)[p];
    float px1 = pr.x - pr.z * 0.5f, py1 = pr.y - pr.w * 0.5f;
    float px2 = pr.x + pr.z * 0.5f, py2 = pr.y + pr.w * 0.5f;
    float parea = (px2 - px1) * (py2 - py1);
    float best = -INFINITY;
    int bix = 0;
    for (int g = 0; g < G_; ++g) {
        float lx = fmaxf(tr[g * 5 + 0], px1), ly = fmaxf(tr[g * 5 + 1], py1);
        float rx = fminf(tr[g * 5 + 2], px2), ry = fminf(tr[g * 5 + 3], py2);
        float w = fmaxf(rx - lx, 0.f), hh = fmaxf(ry - ly, 0.f);
        float inter = w * hh;
        float v = inter / (gA[g] + parea - inter);
        if (v > best) { best = v; bix = g; }  // first-max == jnp.argmax
    }
    best_score[b * P_ + p] = best;
    best_idx[b * P_ + p] = bix;
    if (best > T1_) atomicAdd(&hist[bix], 1);  // LDS atomic only
    __syncthreads();
    if (tid < G_) histA[(b * NBLK_ + blk) * G_ + tid] = hist[tid];
    if (b == 0 && blk == 0 && tid == 0) *done = 0;  // used by kDT, 2 dispatches later
}

// ---------------- kB: match_cnt reduce; normal losses; per-block c_match hist ----------
__global__ __launch_bounds__(256) void kB(
    const float* __restrict__ loc, const float* __restrict__ conf,
    const float* __restrict__ priors, const float* __restrict__ targets,
    const float* __restrict__ best_score, const int* __restrict__ best_idx,
    const int* __restrict__ histA,
    int* __restrict__ histC, int* __restrict__ match_final,
    double* __restrict__ fl_n_p, double* __restrict__ sl_n_p) {
    int tid = threadIdx.x, blk = blockIdx.x, b = blockIdx.y;
    __shared__ float tr[G_ * 5];
    __shared__ float gA[G_];
    __shared__ int outf[G_], hist[G_], mcS[G_];
    __shared__ int iscr[8][G_];
    __shared__ double wred[8];
    if (tid < G_ * 5) tr[tid] = targets[b * G_ * 5 + tid];
    if (tid < G_) hist[tid] = 0;
    {   // match_cnt = sum of 256 per-block hists (L2-hot)
        int part = tid >> 5, g = tid & 31;
        int s = 0;
#pragma unroll 8
        for (int j = 0; j < 32; ++j)
            s += histA[(b * NBLK_ + (part << 5) + j) * G_ + g];
        iscr[part][g] = s;
    }
    __syncthreads();
    if (tid < G_) {
        gA[tid] = (tr[tid * 5 + 2] - tr[tid * 5 + 0]) * (tr[tid * 5 + 3] - tr[tid * 5 + 1]);
        int m = 0;
#pragma unroll
        for (int j = 0; j < 8; ++j) m += iscr[j][tid];
        mcS[tid] = m;
        outf[tid] = (m < K_) ? 1 : 0;
    }
    __syncthreads();
    if (blk == 0 && tid < G_) match_final[b * G_ + tid] = mcS[tid];

    int p = blk * 256 + tid;
    float4 pr = ((const float4*)priors)[p];
    float4 lc = ((const float4*)loc)[(size_t)b * P_ + p];
    float bs = best_score[b * P_ + p];
    int bi = best_idx[b * P_ + p];
    DecBox d = decode_box(pr, lc);
    bool n_pos = bs > T1_;
    float cmax = -INFINITY, mbest = -INFINITY;
    int mg = 0;
    for (int g = 0; g < G_; ++g) {
        float v = iou_dec(d, gA[g], tr[g * 5], tr[g * 5 + 1], tr[g * 5 + 2], tr[g * 5 + 3]);
        cmax = fmaxf(cmax, v);
        bool kill = outf[g] && (bi == g) && n_pos;
        float v2 = kill ? 0.f : v;
        float m = outf[g] ? v2 : -1.f;
        if (m > mbest) { mbest = m; mg = g; }  // first-max
    }
    if (mbest > T2_) atomicAdd(&hist[mg], 1);  // LDS atomic only
    bool ignore = (cmax > T2_) && (bs < T1_);
    bool neg = !(n_pos || ignore);
    double fl = 0.0, sl = 0.0;
    int lab = (int)tr[bi * 5 + 4];
    float2 cf = ((const float2*)conf)[(size_t)b * P_ + p];
    float cfs[2] = {cf.x, cf.y};
#pragma unroll
    for (int c = 0; c < C_; ++c) {
        if (n_pos) fl += (double)focal_f((c == lab) ? 1.f : 0.f, cfs[c], 1.f);
        else if (neg) fl += (double)focal_f(0.f, cfs[c], 1.f);
    }
    if (n_pos) {
        float tx1 = tr[bi * 5], ty1 = tr[bi * 5 + 1];
        float tx2 = tr[bi * 5 + 2], ty2 = tr[bi * 5 + 3];
        float e0 = ((tx1 + tx2) * 0.5f - pr.x) / (V0_ * pr.z);
        float e1 = ((ty1 + ty2) * 0.5f - pr.y) / (V0_ * pr.w);
        float e2 = logf((tx2 - tx1) / pr.z) / V1_;
        float e3 = logf((ty2 - ty1) / pr.w) / V1_;
        sl = (double)sml1(lc.x, e0) + (double)sml1(lc.y, e1) +
             (double)sml1(lc.z, e2) + (double)sml1(lc.w, e3);
    }
    int lane = tid & 63, w = tid >> 6;
    for (int off = 32; off > 0; off >>= 1) {
        fl += __shfl_down(fl, off, 64);
        sl += __shfl_down(sl, off, 64);
    }
    if (lane == 0) { wred[w] = fl; wred[4 + w] = sl; }
    __syncthreads();  // also makes hist[] final
    if (tid == 0) fl_n_p[b * NBLK_ + blk] = wred[0] + wred[1] + wred[2] + wred[3];
    if (tid == 1) sl_n_p[b * NBLK_ + blk] = wred[4] + wred[5] + wred[6] + wred[7];
    if (tid < G_) histC[(b * NBLK_ + blk) * G_ + tid] = hist[tid];
}

// ---------------- kDT: exact-filtered chunk top-5; LAST block runs the tail ------------
__global__ __launch_bounds__(256) void kDT(
    const float* __restrict__ loc, const float* __restrict__ conf,
    const float* __restrict__ priors, const float* __restrict__ targets,
    const float* __restrict__ best_score, const int* __restrict__ best_idx,
    const int* __restrict__ histC, const int* __restrict__ match_final,
    int* __restrict__ cm_final,
    const double* __restrict__ fl_n_p, const double* __restrict__ sl_n_p,
    float* __restrict__ cv5, int* __restrict__ ci5,
    int* __restrict__ done, float* __restrict__ out) {
    int tid = threadIdx.x, bid = blockIdx.x;
    int tb = bid >> 8, tg = (bid >> 3) & 31, tch = bid & (CH_ - 1);
    __shared__ int r4[4];
    __shared__ int flagLast;
    __shared__ union {
        struct { float sv[256 * 5]; int si[256 * 5]; } Dp;
        struct {
            int selp[256][5]; int nS[256];
            double aFlc[B_], aSlc[B_], aFln[B_], aSln[B_];
            int aNp[B_], aCs[B_], aNpc[B_];
        } Tp;
    } u;

    // cm for this (b,g): sum 256 per-block hists
    {
        int v = histC[(tb * NBLK_ + tid) * G_ + tg];
        for (int off = 32; off > 0; off >>= 1) v += __shfl_down(v, off, 64);
        if ((tid & 63) == 0) r4[tid >> 6] = v;
    }
    __syncthreads();
    int cm = r4[0] + r4[1] + r4[2] + r4[3];
    int mc = match_final[tb * G_ + tg];
    if (tch == 0 && tid == 0) cm_final[tb * G_ + tg] = cm;
    int n = (mc < K_) ? min(cm, K_ - mc) : 0;

    if (n > 0) {  // exact sparsity filter — uniform per block
        const float* tgp = targets + (tb * G_ + tg) * 5;
        float tx1 = tgp[0], ty1 = tgp[1], tx2 = tgp[2], ty2 = tgp[3];
        float aa = (tx2 - tx1) * (ty2 - ty1);
        float lv[5];
        int li[5];
#pragma unroll
        for (int k = 0; k < 5; ++k) { lv[k] = -INFINITY; li[k] = 0x7fffffff; }
        int base = tch * CHP_;
        for (int it = 0; it < CHP_ / 256; ++it) {
            int p = base + it * 256 + tid;
            int pbi = best_idx[tb * P_ + p];
            float pbs = best_score[tb * P_ + p];
            float v2;
            if (pbi == tg && pbs > T1_) v2 = 0.f;  // kill (outface true here)
            else {
                float4 pr = ((const float4*)priors)[p];
                float4 lc = ((const float4*)loc)[(size_t)tb * P_ + p];
                v2 = iou_dec(decode_box(pr, lc), aa, tx1, ty1, tx2, ty2);
            }
            top5_insert(v2, p, lv, li);
        }
#pragma unroll
        for (int k = 0; k < 5; ++k) { u.Dp.sv[tid * 5 + k] = lv[k]; u.Dp.si[tid * 5 + k] = li[k]; }
        __syncthreads();
        for (int str = 128; str > 0; str >>= 1) {
            if (tid < str) {
                int a = 0, c = 0;
                float ov[5];
                int oi[5];
#pragma unroll
                for (int k = 0; k < 5; ++k) {
                    float va = u.Dp.sv[tid * 5 + a], vb = u.Dp.sv[(tid + str) * 5 + c];
                    int ia = u.Dp.si[tid * 5 + a], ib = u.Dp.si[(tid + str) * 5 + c];
                    bool ta = (va > vb) || (va == vb && ia < ib);
                    ov[k] = ta ? va : vb;
                    oi[k] = ta ? ia : ib;
                    if (ta) a++; else c++;
                }
#pragma unroll
                for (int k = 0; k < 5; ++k) { u.Dp.sv[tid * 5 + k] = ov[k]; u.Dp.si[tid * 5 + k] = oi[k]; }
            }
            __syncthreads();
        }
        if (tid == 0) {
#pragma unroll
            for (int k = 0; k < 5; ++k) {
                cv5[((tb * G_ + tg) * CH_ + tch) * 5 + k] = u.Dp.sv[k];
                ci5[((tb * G_ + tg) * CH_ + tch) * 5 + k] = u.Dp.si[k];
            }
        }
    }

    // ---- completion counter; last-finished block runs the tail (runs exactly once,
    //      reads only stored partials in fixed order => deterministic output) ----
    __syncthreads();
    if (tid == 0) {
        __threadfence();  // release: all our global stores visible device-wide
        int old = atomicAdd(done, 1);
        flagLast = (old == NTASK_ - 1) ? 1 : 0;
    }
    __syncthreads();
    if (!flagLast) return;
    __threadfence();  // acquire: see all other blocks' stores

    {
        int t = tid, b = t >> 5, g = t & 31;
        int mcT = match_final[t];
        int cmT = cm_final[t];
        int nT = (mcT < K_) ? min(cmT, K_ - mcT) : 0;
        u.Tp.nS[t] = nT;
        float mv[5];
        int mi[5];
#pragma unroll
        for (int k = 0; k < 5; ++k) { mv[k] = -INFINITY; mi[k] = 0x7fffffff; }
        if (nT > 0) {
            for (int ch = 0; ch < CH_; ++ch)
#pragma unroll
                for (int k = 0; k < 5; ++k)
                    top5_insert(cv5[(t * CH_ + ch) * 5 + k], ci5[(t * CH_ + ch) * 5 + k], mv, mi);
        }
#pragma unroll
        for (int k = 0; k < 5; ++k) u.Tp.selp[t][k] = (k < nT) ? mi[k] : -1;
        __syncthreads();

        // override resolution (ascending g: later g wins) + compensation losses
        double flc = 0.0, slc = 0.0;
        int alive = 0;
        float tg0 = targets[t * 5 + 0], tg1 = targets[t * 5 + 1];
        float tg2 = targets[t * 5 + 2], tg3 = targets[t * 5 + 3];
        float labf = targets[t * 5 + 4];
        int labi = (int)labf;
        for (int k = 0; k < nT; ++k) {
            int p = mi[k];
            bool dead = false;
            for (int g2 = g + 1; g2 < G_; ++g2) {
                int q = b * G_ + g2;
                int n2 = u.Tp.nS[q];
                for (int k2 = 0; k2 < n2; ++k2)
                    if (u.Tp.selp[q][k2] == p) dead = true;
            }
            if (!dead) {
                alive++;
                float4 pr = ((const float4*)priors)[p];
                float4 lc = ((const float4*)loc)[(size_t)b * P_ + p];
                float e0 = ((tg0 + tg2) * 0.5f - pr.x) / (V0_ * pr.z);
                float e1 = ((tg1 + tg3) * 0.5f - pr.y) / (V0_ * pr.w);
                float e2 = logf((tg2 - tg0) / pr.z) / V1_;
                float e3 = logf((tg3 - tg1) / pr.w) / V1_;
                slc += (double)sml1(lc.x, e0) + (double)sml1(lc.y, e1) +
                       (double)sml1(lc.z, e2) + (double)sml1(lc.w, e3);
                float2 cf = ((const float2*)conf)[(size_t)b * P_ + p];
                float cfs[2] = {cf.x, cf.y};
#pragma unroll
                for (int c = 0; c < C_; ++c) {
                    float tt = (c == labi) ? labf : 0.f;  // labels[g] * one_hot
                    flc += (double)focal_f(tt, cfs[c], mv[k]);
                }
            }
        }

        // per-b reductions within 32-thread subgroups
        int rmc = mcT, rn = nT, ra = alive;
        double rf = flc, rs = slc;
        double pf = 0.0, ps = 0.0;  // slots [t*8, t*8+8) all belong to image b
        for (int j = 0; j < 8; ++j) { pf += fl_n_p[t * 8 + j]; ps += sl_n_p[t * 8 + j]; }
        for (int off = 16; off > 0; off >>= 1) {
            rmc += __shfl_down(rmc, off, 32);
            rn += __shfl_down(rn, off, 32);
            ra += __shfl_down(ra, off, 32);
            rf += __shfl_down(rf, off, 32);
            rs += __shfl_down(rs, off, 32);
            pf += __shfl_down(pf, off, 32);
            ps += __shfl_down(ps, off, 32);
        }
        if (g == 0) {
            u.Tp.aNp[b] = rmc; u.Tp.aCs[b] = rn; u.Tp.aNpc[b] = ra;
            u.Tp.aFlc[b] = rf; u.Tp.aSlc[b] = rs; u.Tp.aFln[b] = pf; u.Tp.aSln[b] = ps;
        }
        __syncthreads();
        if (t == 0) {
            double sll = 0.0, scl = 0.0;
            for (int b2 = 0; b2 < B_; ++b2) {
                double l_loc = 0.0, l_cls = 0.0;
                int npos = u.Tp.aNp[b2];
                if (npos > 0) {
                    l_cls += u.Tp.aFln[b2] / (double)npos;
                    l_loc += u.Tp.aSln[b2] / (double)npos;
                }
                int csum = u.Tp.aCs[b2];
                if (csum > 0) {
                    int npc = (u.Tp.aNpc[b2] > 1) ? u.Tp.aNpc[b2] : 1;
                    l_loc += u.Tp.aSlc[b2] / (double)npc;
                    l_cls += u.Tp.aFlc[b2] / (double)csum;
                }
                sll += l_loc;
                scl += l_cls;
            }
            out[0] = (float)(sll / B_);
            out[1] = (float)(scl / B_);
        }
    }
}

extern "C" void kernel_launch(void* const* d_in, const int* in_sizes, int n_in,
                              void* d_out, int out_size, void* d_ws, size_t ws_size,
                              hipStream_t stream) {
    (void)in_sizes; (void)n_in; (void)out_size; (void)ws_size;
    const float* loc = (const float*)d_in[0];
    const float* conf = (const float*)d_in[1];
    const float* priors = (const float*)d_in[2];
    const float* targets = (const float*)d_in[3];
    float* out = (float*)d_out;
    char* ws = (char*)d_ws;

    float* best_score = (float*)ws;                               // 2 MB
    int* best_idx = (int*)(ws + (size_t)2 * 1024 * 1024);         // 2 MB
    double* fl_n_p = (double*)(ws + (size_t)4 * 1024 * 1024);     // 16 KB
    double* sl_n_p = fl_n_p + NBLKB_;                             // 16 KB
    float* cv5 = (float*)(sl_n_p + NBLKB_);                       // 40 KB
    int* ci5 = (int*)(cv5 + B_ * G_ * CH_ * 5);                   // 40 KB
    int* histA = ci5 + B_ * G_ * CH_ * 5;                         // 256 KB
    int* histC = histA + NBLKB_ * G_;                             // 256 KB
    int* match_final = histC + NBLKB_ * G_;                       // 1 KB
    int* cm_final = match_final + B_ * G_;                        // 1 KB
    int* done = cm_final + B_ * G_;                               // 4 B

    kA<<<dim3(NBLK_, B_), 256, 0, stream>>>(priors, targets, best_score, best_idx,
                                            histA, done);
    kB<<<dim3(NBLK_, B_), 256, 0, stream>>>(loc, conf, priors, targets,
                                            best_score, best_idx, histA,
                                            histC, match_final, fl_n_p, sl_n_p);
    kDT<<<NTASK_, 256, 0, stream>>>(loc, conf, priors, targets, best_score, best_idx,
                                    histC, match_final, cm_final, fl_n_p, sl_n_p,
                                    cv5, ci5, done, out);
}

// Round 9
// 57.269 us; speedup vs baseline: 4.1814x; 1.5795x over previous
//
#include <hip/hip_runtime.h>

#define B_ 8
#define P_ 65536
#define G_ 32
#define C_ 2
#define K_ 5
#define T1_ 0.35f
#define T2_ 0.5f
#define ALPHA_ 0.25f
#define BETA_ 0.11f
#define V0_ 0.1f
#define V1_ 0.2f

#define ABLK_ 64                  // blocks per image for kA/kB
#define APB_ 1024                 // anchors per block (4 per thread)
#define CH_ 8                     // top-5 chunks per (b,g)
#define CHP_ (P_ / CH_)           // 8192 anchors per chunk
#define NTASK_ (B_ * G_ * CH_)    // 2048 kD blocks

// ws layout (plain-store scratch, every word rewritten each call before any read):
//   [0)      float  best_score[B_*P_]        2 MB
//   +2MB     int    best_idx[B_*P_]          2 MB
//   +4MB     double fl_n_p[512]; sl_n_p[512]           8 KB
//   +..      float  cv5[8*32*8*5]; int ci5[8*32*8*5]   80 KB
//   +..      int    histA[8][32][64]; histC[8][32][64] 128 KB   ([b][g][blk])
//   +..      int    match_final[256]; cm_final[256]    2 KB

// ---------------- numerics helpers (contract off => deterministic across call sites) ----
struct DecBox { float x1, y1, x2, y2, area; };

__device__ __forceinline__ DecBox decode_box(float4 pr, float4 lc) {
#pragma clang fp contract(off)
    DecBox d;
    float dcx = pr.x + lc.x * V0_ * pr.z;
    float dcy = pr.y + lc.y * V0_ * pr.w;
    float dw = pr.z * expf(lc.z * V1_);
    float dh = pr.w * expf(lc.w * V1_);
    d.x1 = dcx - dw * 0.5f; d.y1 = dcy - dh * 0.5f;
    d.x2 = dcx + dw * 0.5f; d.y2 = dcy + dh * 0.5f;
    d.area = (d.x2 - d.x1) * (d.y2 - d.y1);
    return d;
}

__device__ __forceinline__ float iou_dec(DecBox d, float aa,
                                         float tx1, float ty1, float tx2, float ty2) {
#pragma clang fp contract(off)
    float lx = fmaxf(tx1, d.x1), ly = fmaxf(ty1, d.y1);
    float rx = fminf(tx2, d.x2), ry = fminf(ty2, d.y2);
    float w = fmaxf(rx - lx, 0.f), hh = fmaxf(ry - ly, 0.f);
    float inter = w * hh;
    return inter / (aa + d.area - inter);
}

__device__ __forceinline__ float focal_f(float t, float x, float fiou) {
    float ce = fmaxf(x, 0.f) - x * t + log1pf(expf(-fabsf(x)));
    float a = (t * ALPHA_ + (1.f - t) * (1.f - ALPHA_)) * fiou;
    float pt = (t == 1.0f) ? x : 1.f - x;
    float om = 1.f - pt;
    return a * om * om * ce;  // GAMMA = 2
}

__device__ __forceinline__ float sml1(float p, float t) {
    float x = fabsf(p - t);
    return (x >= BETA_) ? (x - 0.5f * BETA_) : (0.5f * x * x / BETA_);
}

// top-5 by (value desc, index asc) — the stable-argsort order
__device__ __forceinline__ void top5_insert(float v, int i, float lv[5], int li[5]) {
    if ((v > lv[4]) || (v == lv[4] && i < li[4])) {
        lv[4] = v; li[4] = i;
#pragma unroll
        for (int k = 4; k > 0; --k) {
            bool sw = (lv[k] > lv[k - 1]) || (lv[k] == lv[k - 1] && li[k] < li[k - 1]);
            if (sw) {
                float tv = lv[k]; lv[k] = lv[k - 1]; lv[k - 1] = tv;
                int ti = li[k]; li[k] = li[k - 1]; li[k - 1] = ti;
            }
        }
    }
}

// ---------------- kA: best match per anchor; per-block hist (plain stores) -------------
__global__ __launch_bounds__(256) void kA(const float* __restrict__ priors,
                                          const float* __restrict__ targets,
                                          float* __restrict__ best_score,
                                          int* __restrict__ best_idx,
                                          int* __restrict__ histA) {
    int tid = threadIdx.x, blk = blockIdx.x, b = blockIdx.y;
    __shared__ float tr[G_ * 5];
    __shared__ float gA[G_];
    __shared__ int hist[G_];
    if (tid < G_ * 5) tr[tid] = targets[b * G_ * 5 + tid];
    if (tid < G_) hist[tid] = 0;
    __syncthreads();
    if (tid < G_)
        gA[tid] = (tr[tid * 5 + 2] - tr[tid * 5 + 0]) * (tr[tid * 5 + 3] - tr[tid * 5 + 1]);
    __syncthreads();
    for (int j = 0; j < 4; ++j) {
        int p = blk * APB_ + j * 256 + tid;
        float4 pr = ((const float4*)priors)[p];
        float px1 = pr.x - pr.z * 0.5f, py1 = pr.y - pr.w * 0.5f;
        float px2 = pr.x + pr.z * 0.5f, py2 = pr.y + pr.w * 0.5f;
        float parea = (px2 - px1) * (py2 - py1);
        float best = -INFINITY;
        int bix = 0;
        for (int g = 0; g < G_; ++g) {
            float lx = fmaxf(tr[g * 5 + 0], px1), ly = fmaxf(tr[g * 5 + 1], py1);
            float rx = fminf(tr[g * 5 + 2], px2), ry = fminf(tr[g * 5 + 3], py2);
            float w = fmaxf(rx - lx, 0.f), hh = fmaxf(ry - ly, 0.f);
            float inter = w * hh;
            float v = inter / (gA[g] + parea - inter);
            if (v > best) { best = v; bix = g; }  // first-max == jnp.argmax
        }
        best_score[b * P_ + p] = best;
        best_idx[b * P_ + p] = bix;
        if (best > T1_) atomicAdd(&hist[bix], 1);  // LDS atomic only
    }
    __syncthreads();
    if (tid < G_) histA[b * (G_ * ABLK_) + tid * ABLK_ + blk] = hist[tid];
}

// ---------------- kB: match_cnt reduce; normal losses; per-block c_match hist ----------
__global__ __launch_bounds__(256) void kB(
    const float* __restrict__ loc, const float* __restrict__ conf,
    const float* __restrict__ priors, const float* __restrict__ targets,
    const float* __restrict__ best_score, const int* __restrict__ best_idx,
    const int* __restrict__ histA,
    int* __restrict__ histC, int* __restrict__ match_final,
    double* __restrict__ fl_n_p, double* __restrict__ sl_n_p) {
    int tid = threadIdx.x, blk = blockIdx.x, b = blockIdx.y;
    __shared__ float tr[G_ * 5];
    __shared__ float gA[G_];
    __shared__ int outf[G_], hist[G_];
    __shared__ double wred[8];
    if (tid < G_ * 5) tr[tid] = targets[b * G_ * 5 + tid];
    if (tid < G_) hist[tid] = 0;
    __syncthreads();
    if (tid < G_)
        gA[tid] = (tr[tid * 5 + 2] - tr[tid * 5 + 0]) * (tr[tid * 5 + 3] - tr[tid * 5 + 1]);
    // match_cnt: 8 threads per g, each sums 8 of the 64 per-block counts (coalesced)
    {
        int g8 = tid >> 3, l8 = tid & 7;
        int s = 0;
#pragma unroll
        for (int j = 0; j < 8; ++j)
            s += histA[b * (G_ * ABLK_) + g8 * ABLK_ + l8 * 8 + j];
        s += __shfl_down(s, 4, 8);
        s += __shfl_down(s, 2, 8);
        s += __shfl_down(s, 1, 8);
        if (l8 == 0) {
            outf[g8] = (s < K_) ? 1 : 0;
            if (blk == 0) match_final[b * G_ + g8] = s;
        }
    }
    __syncthreads();  // gA + outf ready

    double fl = 0.0, sl = 0.0;
    for (int j = 0; j < 4; ++j) {
        int p = blk * APB_ + j * 256 + tid;
        float4 pr = ((const float4*)priors)[p];
        float4 lc = ((const float4*)loc)[(size_t)b * P_ + p];
        float bs = best_score[b * P_ + p];
        int bi = best_idx[b * P_ + p];
        DecBox d = decode_box(pr, lc);
        bool n_pos = bs > T1_;
        float cmax = -INFINITY, mbest = -INFINITY;
        int mg = 0;
        for (int g = 0; g < G_; ++g) {
            float v = iou_dec(d, gA[g], tr[g * 5], tr[g * 5 + 1], tr[g * 5 + 2], tr[g * 5 + 3]);
            cmax = fmaxf(cmax, v);
            bool kill = outf[g] && (bi == g) && n_pos;
            float v2 = kill ? 0.f : v;
            float m = outf[g] ? v2 : -1.f;
            if (m > mbest) { mbest = m; mg = g; }  // first-max
        }
        if (mbest > T2_) atomicAdd(&hist[mg], 1);  // LDS atomic only
        bool ignore = (cmax > T2_) && (bs < T1_);
        bool neg = !(n_pos || ignore);
        int lab = (int)tr[bi * 5 + 4];
        float2 cf = ((const float2*)conf)[(size_t)b * P_ + p];
        float cfs[2] = {cf.x, cf.y};
#pragma unroll
        for (int c = 0; c < C_; ++c) {
            if (n_pos) fl += (double)focal_f((c == lab) ? 1.f : 0.f, cfs[c], 1.f);
            else if (neg) fl += (double)focal_f(0.f, cfs[c], 1.f);
        }
        if (n_pos) {
            float tx1 = tr[bi * 5], ty1 = tr[bi * 5 + 1];
            float tx2 = tr[bi * 5 + 2], ty2 = tr[bi * 5 + 3];
            float e0 = ((tx1 + tx2) * 0.5f - pr.x) / (V0_ * pr.z);
            float e1 = ((ty1 + ty2) * 0.5f - pr.y) / (V0_ * pr.w);
            float e2 = logf((tx2 - tx1) / pr.z) / V1_;
            float e3 = logf((ty2 - ty1) / pr.w) / V1_;
            sl += (double)sml1(lc.x, e0) + (double)sml1(lc.y, e1) +
                  (double)sml1(lc.z, e2) + (double)sml1(lc.w, e3);
        }
    }
    int lane = tid & 63, w = tid >> 6;
    for (int off = 32; off > 0; off >>= 1) {
        fl += __shfl_down(fl, off, 64);
        sl += __shfl_down(sl, off, 64);
    }
    if (lane == 0) { wred[w] = fl; wred[4 + w] = sl; }
    __syncthreads();  // wred + hist final
    if (tid == 0) fl_n_p[b * ABLK_ + blk] = wred[0] + wred[1] + wred[2] + wred[3];
    if (tid == 1) sl_n_p[b * ABLK_ + blk] = wred[4] + wred[5] + wred[6] + wred[7];
    if (tid < G_) histC[b * (G_ * ABLK_) + tid * ABLK_ + blk] = hist[tid];
}

// ---------------- kD: exact-filtered chunk top-5 (no fences, no done counter) ----------
__global__ __launch_bounds__(256) void kD(
    const float* __restrict__ loc, const float* __restrict__ priors,
    const float* __restrict__ targets,
    const float* __restrict__ best_score, const int* __restrict__ best_idx,
    const int* __restrict__ histC, const int* __restrict__ match_final,
    int* __restrict__ cm_final,
    float* __restrict__ cv5, int* __restrict__ ci5) {
    int tid = threadIdx.x, bid = blockIdx.x;
    int tb = bid >> 8, tg = (bid >> 3) & 31, tch = bid & (CH_ - 1);
    __shared__ int cmS;
    // cm for this (b,g): one wave sums the 64 per-block counts (coalesced)
    if (tid < 64) {
        int v = histC[tb * (G_ * ABLK_) + tg * ABLK_ + tid];
        for (int off = 32; off > 0; off >>= 1) v += __shfl_down(v, off, 64);
        if (tid == 0) cmS = v;
    }
    __syncthreads();
    int cm = cmS;
    int mc = match_final[tb * G_ + tg];
    if (tch == 0 && tid == 0) cm_final[tb * G_ + tg] = cm;
    int n = (mc < K_) ? min(cm, K_ - mc) : 0;
    if (n <= 0) return;  // exact sparsity filter — uniform per block

    const float* tgp = targets + (tb * G_ + tg) * 5;
    float tx1 = tgp[0], ty1 = tgp[1], tx2 = tgp[2], ty2 = tgp[3];
    float aa = (tx2 - tx1) * (ty2 - ty1);
    float lv[5];
    int li[5];
#pragma unroll
    for (int k = 0; k < 5; ++k) { lv[k] = -INFINITY; li[k] = 0x7fffffff; }
    int base = tch * CHP_;
    for (int it = 0; it < CHP_ / 256; ++it) {
        int p = base + it * 256 + tid;
        int pbi = best_idx[tb * P_ + p];
        float pbs = best_score[tb * P_ + p];
        float v2;
        if (pbi == tg && pbs > T1_) v2 = 0.f;  // kill (outface true here)
        else {
            float4 pr = ((const float4*)priors)[p];
            float4 lc = ((const float4*)loc)[(size_t)tb * P_ + p];
            v2 = iou_dec(decode_box(pr, lc), aa, tx1, ty1, tx2, ty2);
        }
        top5_insert(v2, p, lv, li);
    }
    __shared__ float sv[256 * 5];
    __shared__ int si[256 * 5];
#pragma unroll
    for (int k = 0; k < 5; ++k) { sv[tid * 5 + k] = lv[k]; si[tid * 5 + k] = li[k]; }
    __syncthreads();
    for (int str = 128; str > 0; str >>= 1) {
        if (tid < str) {
            int a = 0, c = 0;
            float ov[5];
            int oi[5];
#pragma unroll
            for (int k = 0; k < 5; ++k) {
                float va = sv[tid * 5 + a], vb = sv[(tid + str) * 5 + c];
                int ia = si[tid * 5 + a], ib = si[(tid + str) * 5 + c];
                bool ta = (va > vb) || (va == vb && ia < ib);
                ov[k] = ta ? va : vb;
                oi[k] = ta ? ia : ib;
                if (ta) a++; else c++;
            }
#pragma unroll
            for (int k = 0; k < 5; ++k) { sv[tid * 5 + k] = ov[k]; si[tid * 5 + k] = oi[k]; }
        }
        __syncthreads();
    }
    if (tid == 0) {
#pragma unroll
        for (int k = 0; k < 5; ++k) {
            cv5[((tb * G_ + tg) * CH_ + tch) * 5 + k] = sv[k];
            ci5[((tb * G_ + tg) * CH_ + tch) * 5 + k] = si[k];
        }
    }
}

// ---------------- kTail: merge top-5s, override resolution, comp losses, finalize ------
__global__ __launch_bounds__(256) void kTail(
    const float* __restrict__ loc, const float* __restrict__ conf,
    const float* __restrict__ priors, const float* __restrict__ targets,
    const int* __restrict__ match_final, const int* __restrict__ cm_final,
    const double* __restrict__ fl_n_p, const double* __restrict__ sl_n_p,
    const float* __restrict__ cv5, const int* __restrict__ ci5,
    float* __restrict__ out) {
    int t = threadIdx.x, b = t >> 5, g = t & 31;
    __shared__ int selp[256][5];
    __shared__ int nS[256];
    __shared__ double aFlc[B_], aSlc[B_], aFln[B_], aSln[B_];
    __shared__ int aNp[B_], aCs[B_], aNpc[B_];

    int mc = match_final[t];
    int cm = cm_final[t];
    int n = (mc < K_) ? min(cm, K_ - mc) : 0;
    nS[t] = n;
    float mv[5];
    int mi[5];
#pragma unroll
    for (int k = 0; k < 5; ++k) { mv[k] = -INFINITY; mi[k] = 0x7fffffff; }
    if (n > 0) {
        for (int ch = 0; ch < CH_; ++ch)
#pragma unroll
            for (int k = 0; k < 5; ++k)
                top5_insert(cv5[(t * CH_ + ch) * 5 + k], ci5[(t * CH_ + ch) * 5 + k], mv, mi);
    }
#pragma unroll
    for (int k = 0; k < 5; ++k) selp[t][k] = (k < n) ? mi[k] : -1;
    __syncthreads();

    // override resolution (ascending g: later g wins) + compensation losses
    double flc = 0.0, slc = 0.0;
    int alive = 0;
    float tg0 = targets[t * 5 + 0], tg1 = targets[t * 5 + 1];
    float tg2 = targets[t * 5 + 2], tg3 = targets[t * 5 + 3];
    float labf = targets[t * 5 + 4];
    int labi = (int)labf;
    for (int k = 0; k < n; ++k) {
        int p = mi[k];
        bool dead = false;
        for (int g2 = g + 1; g2 < G_; ++g2) {
            int q = b * G_ + g2;
            int n2 = nS[q];
            for (int k2 = 0; k2 < n2; ++k2)
                if (selp[q][k2] == p) dead = true;
        }
        if (!dead) {
            alive++;
            float4 pr = ((const float4*)priors)[p];
            float4 lc = ((const float4*)loc)[(size_t)b * P_ + p];
            float e0 = ((tg0 + tg2) * 0.5f - pr.x) / (V0_ * pr.z);
            float e1 = ((tg1 + tg3) * 0.5f - pr.y) / (V0_ * pr.w);
            float e2 = logf((tg2 - tg0) / pr.z) / V1_;
            float e3 = logf((tg3 - tg1) / pr.w) / V1_;
            slc += (double)sml1(lc.x, e0) + (double)sml1(lc.y, e1) +
                   (double)sml1(lc.z, e2) + (double)sml1(lc.w, e3);
            float2 cf = ((const float2*)conf)[(size_t)b * P_ + p];
            float cfs[2] = {cf.x, cf.y};
#pragma unroll
            for (int c = 0; c < C_; ++c) {
                float tt = (c == labi) ? labf : 0.f;  // labels[g] * one_hot
                flc += (double)focal_f(tt, cfs[c], mv[k]);
            }
        }
    }

    // per-b reductions within 32-thread subgroups (64 partial slots per image)
    int rmc = mc, rn = n, ra = alive;
    double rf = flc, rs = slc;
    double pf = 0.0, ps = 0.0;
    for (int j = 0; j < 2; ++j) {
        pf += fl_n_p[b * ABLK_ + g * 2 + j];
        ps += sl_n_p[b * ABLK_ + g * 2 + j];
    }
    for (int off = 16; off > 0; off >>= 1) {
        rmc += __shfl_down(rmc, off, 32);
        rn += __shfl_down(rn, off, 32);
        ra += __shfl_down(ra, off, 32);
        rf += __shfl_down(rf, off, 32);
        rs += __shfl_down(rs, off, 32);
        pf += __shfl_down(pf, off, 32);
        ps += __shfl_down(ps, off, 32);
    }
    if (g == 0) {
        aNp[b] = rmc; aCs[b] = rn; aNpc[b] = ra;
        aFlc[b] = rf; aSlc[b] = rs; aFln[b] = pf; aSln[b] = ps;
    }
    __syncthreads();
    if (t == 0) {
        double sll = 0.0, scl = 0.0;
        for (int b2 = 0; b2 < B_; ++b2) {
            double l_loc = 0.0, l_cls = 0.0;
            int npos = aNp[b2];
            if (npos > 0) {
                l_cls += aFln[b2] / (double)npos;
                l_loc += aSln[b2] / (double)npos;
            }
            int csum = aCs[b2];
            if (csum > 0) {
                int npc = (aNpc[b2] > 1) ? aNpc[b2] : 1;
                l_loc += aSlc[b2] / (double)npc;
                l_cls += aFlc[b2] / (double)csum;
            }
            sll += l_loc;
            scl += l_cls;
        }
        out[0] = (float)(sll / B_);
        out[1] = (float)(scl / B_);
    }
}

extern "C" void kernel_launch(void* const* d_in, const int* in_sizes, int n_in,
                              void* d_out, int out_size, void* d_ws, size_t ws_size,
                              hipStream_t stream) {
    (void)in_sizes; (void)n_in; (void)out_size; (void)ws_size;
    const float* loc = (const float*)d_in[0];
    const float* conf = (const float*)d_in[1];
    const float* priors = (const float*)d_in[2];
    const float* targets = (const float*)d_in[3];
    float* out = (float*)d_out;
    char* ws = (char*)d_ws;

    float* best_score = (float*)ws;                               // 2 MB
    int* best_idx = (int*)(ws + (size_t)2 * 1024 * 1024);         // 2 MB
    double* fl_n_p = (double*)(ws + (size_t)4 * 1024 * 1024);     // 512 doubles
    double* sl_n_p = fl_n_p + B_ * ABLK_;                         // 512 doubles
    float* cv5 = (float*)(sl_n_p + B_ * ABLK_);                   // 10240 floats
    int* ci5 = (int*)(cv5 + B_ * G_ * CH_ * 5);                   // 10240 ints
    int* histA = ci5 + B_ * G_ * CH_ * 5;                         // 16K ints
    int* histC = histA + B_ * G_ * ABLK_;                         // 16K ints
    int* match_final = histC + B_ * G_ * ABLK_;                   // 256 ints
    int* cm_final = match_final + B_ * G_;                        // 256 ints

    kA<<<dim3(ABLK_, B_), 256, 0, stream>>>(priors, targets, best_score, best_idx, histA);
    kB<<<dim3(ABLK_, B_), 256, 0, stream>>>(loc, conf, priors, targets,
                                            best_score, best_idx, histA,
                                            histC, match_final, fl_n_p, sl_n_p);
    kD<<<NTASK_, 256, 0, stream>>>(loc, priors, targets, best_score, best_idx,
                                   histC, match_final, cm_final, cv5, ci5);
    kTail<<<1, 256, 0, stream>>>(loc, conf, priors, targets, match_final, cm_final,
                                 fl_n_p, sl_n_p, cv5, ci5, out);
}